// Round 1
// baseline (275.690 us; speedup 1.0000x reference)
//
#include <hip/hip_runtime.h>
#include <math.h>
#include <float.h>

#define Mdim 64
#define Ldim 32
#define Pdim 100
#define NCdim 400
#define EVALS_PER_P (NCdim + 1)            // 401
#define EVALS_PER_WAVE 256                 // 4 per lane (v4 fp32)
#define WAVES_PER_M 157                    // ceil(64*100*401 / (64m) / 256) = ceil(40100/256)
#define BLOCKS_PER_M 40                    // ceil(157/4), 4 waves/block
#define NPTS (Mdim * Pdim)                 // 6400
#define WSLOT (Mdim * WAVES_PER_M)         // 10048 part slots
#define TWO_PI_F 6.28318530717958647692f
#define INV_2PI_F 0.15915494309189535f
#define NLOG2E_F (-1.4426950408889634f)
#define LOG2_10TH (-3.3219280948873623f)   // log2(0.1)

typedef float v4 __attribute__((ext_vector_type(4)));

__device__ __forceinline__ v4 mk4(float a, float b, float c, float d) {
    v4 r; r.x = a; r.y = b; r.z = c; r.w = d; return r;
}
__device__ __forceinline__ v4 sel4(bool c0, bool c1, bool c2, bool c3, v4 a, v4 b) {
    return mk4(c0 ? a.x : b.x, c1 ? a.y : b.y, c2 ? a.z : b.z, c3 ? a.w : b.w);
}
__device__ __forceinline__ v4 abs4(v4 a) {
    return mk4(fabsf(a.x), fabsf(a.y), fabsf(a.z), fabsf(a.w));
}
__device__ __forceinline__ v4 rsq4(v4 a) {
    return mk4(__builtin_amdgcn_rsqf(a.x), __builtin_amdgcn_rsqf(a.y),
               __builtin_amdgcn_rsqf(a.z), __builtin_amdgcn_rsqf(a.w));
}
__device__ __forceinline__ v4 sqrt4(v4 a) {
    return mk4(__builtin_amdgcn_sqrtf(a.x), __builtin_amdgcn_sqrtf(a.y),
               __builtin_amdgcn_sqrtf(a.z), __builtin_amdgcn_sqrtf(a.w));
}
__device__ __forceinline__ v4 sin4(v4 a) {
    return mk4(__builtin_amdgcn_sinf(a.x), __builtin_amdgcn_sinf(a.y),
               __builtin_amdgcn_sinf(a.z), __builtin_amdgcn_sinf(a.w));
}
__device__ __forceinline__ v4 cos4(v4 a) {
    return mk4(__builtin_amdgcn_cosf(a.x), __builtin_amdgcn_cosf(a.y),
               __builtin_amdgcn_cosf(a.z), __builtin_amdgcn_cosf(a.w));
}
__device__ __forceinline__ v4 exp24(v4 a) {
    return mk4(__builtin_amdgcn_exp2f(a.x), __builtin_amdgcn_exp2f(a.y),
               __builtin_amdgcn_exp2f(a.z), __builtin_amdgcn_exp2f(a.w));
}

// Per-layer, m-uniform, omega-free parameters. 32 B -> 2x ds_read_b128.
// dm is pre-folded with the trans-argument scalings (saves 2 v4 muls/layer);
// inv_rho2 dropped (recomputed as inv_rm^2, 1 scalar op) to keep 8 floats.
struct alignas(16) LayerP {
    float inv_a2;    // 1/a^2
    float inv_b2;    // 1/b^2
    float b2two;     // 2*b^2
    float rm;        // rho
    float inv_rm;    // 1/rho
    float rho2;      // rho^2
    float dm_i2p;    // dm / (2*pi)   (v_sin/v_cos take revolutions)
    float dm_nle;    // dm * -log2(e) (exp(-p) = exp2(-p*log2e))
};

// One layer of the Dunkin recursion on a packed 4-eval group.
// x = ra2*w and z = rb2*y identities eliminate the x/z select chains.
template <bool RENORM>
__device__ __forceinline__ void layer_step(const LayerP L,
                                           const v4 wvno2, const v4 wvno4, const v4 tneg,
                                           const v4 om2, const v4 invom2,
                                           v4& e0, v4& e1, v4& e2, v4& e3, v4& e4)
{
    const v4 ra2 = wvno2 - om2 * L.inv_a2;   // sign = regime
    const v4 rb2 = wvno2 - om2 * L.inv_b2;

    const v4 abs_ra2 = abs4(ra2);
    const v4 abs_rb2 = abs4(rb2);
    const v4 inv_ra = rsq4(abs_ra2);          // rsq replaces sqrt+rcp
    const v4 inv_rb = rsq4(abs_rb2);
    const v4 ra = abs_ra2 * inv_ra;
    const v4 rb = abs_rb2 * inv_rb;
    const v4 gammk = L.b2two * invom2;
    const v4 gam   = gammk * wvno2;

    // Raw HW transcendentals; dm-folded packed argument scaling.
    const v4 ppr = ra * L.dm_i2p;
    const v4 qqr = rb * L.dm_i2p;
    const v4 pe  = ra * L.dm_nle;
    const v4 qe  = rb * L.dm_nle;
    const v4 sp  = sin4(ppr);
    const v4 cp  = cos4(ppr);
    const v4 sq  = sin4(qqr);
    const v4 cq  = cos4(qqr);
    const v4 e_p = exp24(pe);
    const v4 e_q = exp24(qe);

    const v4 fac_p = e_p * e_p;              // exp(-2p)
    const v4 fac_q = e_q * e_q;
    const v4 cosp_e = 0.5f * fac_p + 0.5f;
    const v4 sinp_e = -0.5f * fac_p + 0.5f;
    const v4 cosq_e = 0.5f * fac_q + 0.5f;
    const v4 sinq_e = -0.5f * fac_q + 0.5f;

    const bool la0 = ra2.x < 0.0f, la1 = ra2.y < 0.0f, la2 = ra2.z < 0.0f, la3 = ra2.w < 0.0f;
    const bool lb0 = rb2.x < 0.0f, lb1 = rb2.y < 0.0f, lb2 = rb2.z < 0.0f, lb3 = rb2.w < 0.0f;

    const v4 one = mk4(1.0f, 1.0f, 1.0f, 1.0f);
    const v4 cosp = sel4(la0, la1, la2, la3, cp, cosp_e);
    const v4 w    = sel4(la0, la1, la2, la3, sp, sinp_e) * inv_ra;
    const v4 cosq = sel4(lb0, lb1, lb2, lb3, cq, cosq_e);
    const v4 y    = sel4(lb0, lb1, lb2, lb3, sq, sinq_e) * inv_rb;
    const v4 a0   = sel4(la0, la1, la2, la3, one, e_p)
                  * sel4(lb0, lb1, lb2, lb3, one, e_q);

    const v4 cpcq = cosp * cosq;
    const v4 cpy  = cosp * y;
    const v4 cqw  = cosq * w;
    const v4 wy   = w * y;
    const v4 cpz  = rb2 * cpy;
    const v4 cqx  = ra2 * cqw;
    const v4 wz   = rb2 * wy;
    const v4 xy   = ra2 * wy;
    const v4 xz   = ra2 * wz;

    // ---- _dnka (c20/c21/c23/c24 folded into et2 = tneg*e2) ----
    const v4 gamm1 = gam - 1.0f;
    const v4 twgm1 = gam + gamm1;
    const v4 gmgmk = gam * gammk;
    const v4 gmgm1 = gam * gamm1;
    const v4 gm1sq = gamm1 * gamm1;
    const v4 a0pq  = a0 - cpcq;
    const float irho2 = L.inv_rm * L.inv_rm;

    const v4 c00 = cpcq - 2.0f * gmgm1 * a0pq - gmgmk * xz - wvno2 * gm1sq * wy;
    const v4 c01 = (wvno2 * cpy - cqx) * L.inv_rm;
    const v4 c02 = -(twgm1 * a0pq + gammk * xz + wvno2 * gamm1 * wy) * L.inv_rm;
    const v4 c03 = (cpz - wvno2 * cqw) * L.inv_rm;
    const v4 c04 = -(2.0f * wvno2 * a0pq + xz + wvno4 * wy) * irho2;
    const v4 c10 = (gmgmk * cpz - gm1sq * cqw) * L.rm;
    const v4 c11 = cpcq;
    const v4 c12 = gammk * cpz - gamm1 * cqw;
    const v4 c13 = -wz;
    const v4 c30 = (gm1sq * cpy - gmgmk * cqx) * L.rm;
    const v4 c31 = -xy;
    const v4 c32 = gamm1 * cpy - gammk * cqx;
    const v4 c40 = -(2.0f * gmgmk * gm1sq * a0pq + gmgmk * gmgmk * xz
                     + gm1sq * gm1sq * wy) * L.rho2;
    const v4 c42 = -(gammk * gamm1 * twgm1 * a0pq + gam * gammk * gammk * xz
                     + gamm1 * gm1sq * wy) * L.rm;
    const v4 c22 = a0 + 2.0f * (cpcq - c00);

    const v4 et2 = tneg * e2;   // folds the tneg-scaled row-2 coefficients

    // ---- ee = e . ca ----
    const v4 ee0 = e0 * c00 + e1 * c10 + et2 * c42 + e3 * c30 + e4 * c40;
    const v4 ee1 = e0 * c01 + e1 * c11 + et2 * c32 + e3 * c31 + e4 * c30;
    const v4 ee2 = e0 * c02 + e1 * c12 + e2  * c22 + e3 * c32 + e4 * c42;
    const v4 ee3 = e0 * c03 + e1 * c13 + et2 * c12 + e3 * c11 + e4 * c10;
    const v4 ee4 = e0 * c04 + e1 * c03 + et2 * c02 + e3 * c01 + e4 * c00;

    if constexpr (RENORM) {
        float t0 = fmaxf(fmaxf(fabsf(ee0.x), fabsf(ee1.x)), fabsf(ee2.x));
        t0 = fmaxf(t0, fmaxf(fabsf(ee3.x), fabsf(ee4.x)));
        float t1 = fmaxf(fmaxf(fabsf(ee0.y), fabsf(ee1.y)), fabsf(ee2.y));
        t1 = fmaxf(t1, fmaxf(fabsf(ee3.y), fabsf(ee4.y)));
        float t2 = fmaxf(fmaxf(fabsf(ee0.z), fabsf(ee1.z)), fabsf(ee2.z));
        t2 = fmaxf(t2, fmaxf(fabsf(ee3.z), fabsf(ee4.z)));
        float t3 = fmaxf(fmaxf(fabsf(ee0.w), fabsf(ee1.w)), fabsf(ee2.w));
        t3 = fmaxf(t3, fmaxf(fabsf(ee3.w), fabsf(ee4.w)));
        t0 = fmaxf(t0, 1e-30f);
        t1 = fmaxf(t1, 1e-30f);
        t2 = fmaxf(t2, 1e-30f);
        t3 = fmaxf(t3, 1e-30f);
        const v4 inv = mk4(__builtin_amdgcn_rcpf(t0), __builtin_amdgcn_rcpf(t1),
                           __builtin_amdgcn_rcpf(t2), __builtin_amdgcn_rcpf(t3));
        e0 = ee0 * inv;
        e1 = ee1 * inv;
        e2 = ee2 * inv;
        e3 = ee3 * inv;
        e4 = ee4 * inv;
    } else {
        e0 = ee0; e1 = ee1; e2 = ee2; e3 = ee3; e4 = ee4;
    }
}

// Packed Dunkin-recursion determinant: FOUR independent evals per lane.
__device__ __forceinline__ v4 dltar4_pk(v4 wvno2, v4 om2, v4 invom2,
                                        const LayerP* __restrict__ slay)
{
    const v4 wvno4 = wvno2 * wvno2;
    const v4 tneg  = -2.0f * wvno2;

    // ---- halfspace init ----
    const LayerP H = slay[Ldim - 1];
    const v4 ra2h = wvno2 - om2 * H.inv_a2;
    const v4 rb2h = wvno2 - om2 * H.inv_b2;
    const v4 ra_h = sqrt4(abs4(ra2h));
    const v4 rb_h = sqrt4(abs4(rb2h));
    const v4 gammk_h = H.b2two * invom2;
    const v4 gam_h   = gammk_h * wvno2;
    const v4 gamm1_h = gam_h - 1.0f;
    const v4 rarb_h  = ra_h * rb_h;
    v4 e0 = H.rho2 * (gamm1_h * gamm1_h - gam_h * gammk_h * rarb_h);
    v4 e1 = -H.rm * ra_h;
    v4 e2 = H.rm * (gamm1_h - gammk_h * rarb_h);
    v4 e3 = H.rm * rb_h;
    v4 e4 = wvno2 - rarb_h;

    // l = 30 (even -> renorm), then 15 pairs (29,28) .. (1,0).
    // By-value LayerP: both ds_read pairs issue before the first step
    // of each pair -> second layer's params prefetch under compute.
    layer_step<true>(slay[Ldim - 2], wvno2, wvno4, tneg, om2, invom2,
                     e0, e1, e2, e3, e4);
    for (int l = Ldim - 3; l >= 1; l -= 2) {
        const LayerP Lo = slay[l];
        const LayerP Le = slay[l - 1];
        layer_step<false>(Lo, wvno2, wvno4, tneg, om2, invom2,
                          e0, e1, e2, e3, e4);
        layer_step<true> (Le, wvno2, wvno4, tneg, om2, invom2,
                          e0, e1, e2, e3, e4);
    }
    return e0;
}

// Per-component (p,c) decode from flat eval index S + OFS + lane.
#define DECODE(SUF, OFS)                                                      \
    int c_##SUF = c0 + (OFS) + lane;                                          \
    const bool cr_##SUF = c_##SUF >= EVALS_PER_P;                             \
    const int p_##SUF = p0 + (cr_##SUF ? 1 : 0);                              \
    c_##SUF = cr_##SUF ? c_##SUF - EVALS_PER_P : c_##SUF;                     \
    const bool valid_##SUF = p_##SUF < Pdim;                                  \
    const int mp_##SUF = m * Pdim + (valid_##SUF ? p_##SUF : 0);              \
    const float om_##SUF = fmaxf(TWO_PI_F / tlist[mp_##SUF], 1.0e-4f);        \
    const bool isC_##SUF = c_##SUF < NCdim;                                   \
    const float den_##SUF = isC_##SUF ? Clist[c_##SUF] : vlist[mp_##SUF];     \
    const float wv_##SUF = om_##SUF * __builtin_amdgcn_rcpf(den_##SUF);

// Main kernel: FOUR evals per lane. Block = 4 waves, all same m.
// Wave wv covers flat evals [S, S+256). Per-wave segment max/min go to
// DEDICATED slots (pAmx/pAmn for the wave's first p, pBmx/pBmn for the
// crossed-into p) -- plain stores, no init kernel, no atomics. Sentinel
// +/-FLT_MAX are the neutral elements for partially-covering waves.
__global__ __launch_bounds__(256, 4)
void disp_kernel(const float* __restrict__ vlist, const float* __restrict__ tlist,
                 const float* __restrict__ dth,  const float* __restrict__ bvel,
                 const float* __restrict__ Clist,
                 float* __restrict__ pAmx, float* __restrict__ pAmn,
                 float* __restrict__ pBmx, float* __restrict__ pBmn,
                 float* __restrict__ e00f)
{
    __shared__ LayerP slay[Ldim];

    const int bid = blockIdx.x;
    const int m   = bid / BLOCKS_PER_M;
    const int wb  = bid - m * BLOCKS_PER_M;
    const int tid  = threadIdx.x;
    const int wid  = tid >> 6;
    const int lane = tid & 63;
    const int wv   = wb * 4 + wid;            // wave index within m

    if (tid < Ldim) {
        const float bb = bvel[m * Ldim + tid];
        const float b2 = bb * bb;
        const float b3 = b2 * bb;
        const float b4 = b2 * b2;
        const float aa = 0.9409f + 2.0947f * bb - 0.8206f * b2
                         + 0.2683f * b3 - 0.0251f * b4;
        const float a2 = aa * aa;
        const float a3 = a2 * aa;
        const float a4 = a2 * a2;
        const float a5 = a4 * aa;
        const float rr = 1.6612f * aa - 0.4721f * a2 + 0.0671f * a3
                         - 0.0043f * a4 + 0.000106f * a5;
        const float dmv = dth[m * Ldim + tid];
        LayerP Lp;
        Lp.inv_a2 = 1.0f / (aa * aa);
        Lp.inv_b2 = 1.0f / (bb * bb);
        Lp.b2two  = 2.0f * bb * bb;
        Lp.rm     = rr;
        Lp.inv_rm = 1.0f / rr;
        Lp.rho2   = rr * rr;
        Lp.dm_i2p = dmv * INV_2PI_F;
        Lp.dm_nle = dmv * NLOG2E_F;
        slay[tid] = Lp;
    }
    __syncthreads();

    if (wv >= WAVES_PER_M) return;            // idle waves (after barrier)

    // Decode (p, c) for the four evals of this lane.
    const int S  = wv * EVALS_PER_WAVE;
    const int p0 = S / EVALS_PER_P;           // magic-mul const divide
    const int c0 = S - p0 * EVALS_PER_P;

    DECODE(x, 0)
    DECODE(y, 64)
    DECODE(z, 128)
    DECODE(w, 192)

    const v4 om  = mk4(om_x, om_y, om_z, om_w);
    const v4 wvn = mk4(wv_x, wv_y, wv_z, wv_w);
    const v4 om2 = om * om;
    const v4 invom2 = mk4(__builtin_amdgcn_rcpf(om2.x), __builtin_amdgcn_rcpf(om2.y),
                          __builtin_amdgcn_rcpf(om2.z), __builtin_amdgcn_rcpf(om2.w));
    const v4 wvno2 = wvn * wvn;

    const v4 det = dltar4_pk(wvno2, om2, invom2, slay);

    // e00 stores (exactly one lane/eval per (m,p) has c == NCdim).
    if (valid_x && !isC_x) e00f[m * Pdim + p_x] = det.x;
    if (valid_y && !isC_y) e00f[m * Pdim + p_y] = det.y;
    if (valid_z && !isC_z) e00f[m * Pdim + p_z] = det.z;
    if (valid_w && !isC_w) e00f[m * Pdim + p_w] = det.w;

    // Segmented reduction over the wave's <=2 p-segments (pA/pB wave-uniform).
    const int pA = p0;
    const int pB = p0 + ((c0 + EVALS_PER_WAVE - 1) >= EVALS_PER_P ? 1 : 0);
    const int slot = m * WAVES_PER_M + wv;

    {
        const bool iAx = valid_x && isC_x && (p_x == pA);
        const bool iAy = valid_y && isC_y && (p_y == pA);
        const bool iAz = valid_z && isC_z && (p_z == pA);
        const bool iAw = valid_w && isC_w && (p_w == pA);
        float mxA = fmaxf(fmaxf(iAx ? det.x : -FLT_MAX, iAy ? det.y : -FLT_MAX),
                          fmaxf(iAz ? det.z : -FLT_MAX, iAw ? det.w : -FLT_MAX));
        float mnA = fminf(fminf(iAx ? det.x :  FLT_MAX, iAy ? det.y :  FLT_MAX),
                          fminf(iAz ? det.z :  FLT_MAX, iAw ? det.w :  FLT_MAX));
        for (int off = 32; off >= 1; off >>= 1) {
            mxA = fmaxf(mxA, __shfl_xor(mxA, off));
            mnA = fminf(mnA, __shfl_xor(mnA, off));
        }
        if (lane == 0) {
            pAmx[slot] = mxA;
            pAmn[slot] = mnA;
        }
    }
    if (pB != pA) {                           // wave-uniform branch
        const bool iBx = valid_x && isC_x && (p_x == pB);
        const bool iBy = valid_y && isC_y && (p_y == pB);
        const bool iBz = valid_z && isC_z && (p_z == pB);
        const bool iBw = valid_w && isC_w && (p_w == pB);
        float mxB = fmaxf(fmaxf(iBx ? det.x : -FLT_MAX, iBy ? det.y : -FLT_MAX),
                          fmaxf(iBz ? det.z : -FLT_MAX, iBw ? det.w : -FLT_MAX));
        float mnB = fminf(fminf(iBx ? det.x :  FLT_MAX, iBy ? det.y :  FLT_MAX),
                          fminf(iBz ? det.z :  FLT_MAX, iBw ? det.w :  FLT_MAX));
        for (int off = 32; off >= 1; off >>= 1) {
            mxB = fmaxf(mxB, __shfl_xor(mxB, off));
            mnB = fminf(mnB, __shfl_xor(mnB, off));
        }
        if (lane == 0 && pB < Pdim) {
            pBmx[slot] = mxB;
            pBmn[slot] = mnB;
        }
    }
}

// Epilogue: one wave per m. Reconstructs per-p max/min from the <=3 covering
// wave slots, sums the 100 per-p terms + damping, writes out[m].
__global__ __launch_bounds__(64)
void epilogue_kernel(const float* __restrict__ pAmx, const float* __restrict__ pAmn,
                     const float* __restrict__ pBmx, const float* __restrict__ pBmn,
                     const float* __restrict__ e00f, const float* __restrict__ bvel,
                     float* __restrict__ out)
{
    const int m    = blockIdx.x;
    const int lane = threadIdx.x;

    float acc = 0.0f;
    for (int p = lane; p < Pdim; p += 64) {
        const int w0 = (EVALS_PER_P * p) / EVALS_PER_WAVE;
        const int w1 = (EVALS_PER_P * p + NCdim - 1) / EVALS_PER_WAVE;
        float mx = -FLT_MAX, mn = FLT_MAX;
        for (int w = w0; w <= w1; ++w) {
            const int s = m * WAVES_PER_M + w;
            const int pAw = (w * EVALS_PER_WAVE) / EVALS_PER_P;
            const float vmx = (pAw == p) ? pAmx[s] : pBmx[s];
            const float vmn = (pAw == p) ? pAmn[s] : pBmn[s];
            mx = fmaxf(mx, vmx);
            mn = fminf(mn, vmn);
        }
        const float en = e00f[m * Pdim + p] / (mx - mn);
        acc += 1.0f - __builtin_amdgcn_exp2f(fabsf(en) * LOG2_10TH); // 1-0.1^|en|
    }

    // damping term
    float damp = 0.0f;
    if (lane < Ldim) {
        const float bb    = bvel[m * Ldim + lane];
        const float bprev = bvel[m * Ldim + ((lane == 0) ? 0 : lane - 1)];
        const float bnext = bvel[m * Ldim + ((lane == Ldim - 1) ? Ldim - 1 : lane + 1)];
        float tval;
        if (lane == 0)             tval = bb - bnext;
        else if (lane == Ldim - 1) tval = bb - bprev;
        else                       tval = 2.0f * bb - bprev - bnext;
        damp = fabsf(tval * (1.0f / (float)Ldim));
    }

    float tot = fmaf(acc, 1.0f / (float)Pdim, damp);
    for (int off = 32; off >= 1; off >>= 1)
        tot += __shfl_xor(tot, off);
    if (lane == 0) out[m] = tot;
}

extern "C" void kernel_launch(void* const* d_in, const int* in_sizes, int n_in,
                              void* d_out, int out_size, void* d_ws, size_t ws_size,
                              hipStream_t stream)
{
    const float* vlist = (const float*)d_in[0];
    const float* tlist = (const float*)d_in[1];
    const float* dth   = (const float*)d_in[2];
    const float* bvel  = (const float*)d_in[3];
    const float* Clist = (const float*)d_in[4];
    float* out = (float*)d_out;

    float* pAmx = (float*)d_ws;            // [WSLOT]
    float* pAmn = pAmx + WSLOT;
    float* pBmx = pAmn + WSLOT;
    float* pBmn = pBmx + WSLOT;
    float* e00f = pBmn + WSLOT;            // [NPTS]

    hipLaunchKernelGGL(disp_kernel, dim3(Mdim * BLOCKS_PER_M), dim3(256), 0, stream,
                       vlist, tlist, dth, bvel, Clist, pAmx, pAmn, pBmx, pBmn, e00f);
    hipLaunchKernelGGL(epilogue_kernel, dim3(Mdim), dim3(64), 0, stream,
                       pAmx, pAmn, pBmx, pBmn, e00f, bvel, out);
}

// Round 2
// 255.977 us; speedup vs baseline: 1.0770x; 1.0770x over previous
//
#include <hip/hip_runtime.h>
#include <math.h>
#include <float.h>

#define Mdim 64
#define Ldim 32
#define Pdim 100
#define NCdim 400
#define EVALS_PER_P (NCdim + 1)            // 401
#define EVALS_PER_WAVE 128                 // 2 per lane (packed fp32)
#define WAVES_PER_M 314                    // ceil(40100/128)
#define BLOCKS_PER_M 79                    // ceil(314/4), 4 waves/block
#define NPTS (Mdim * Pdim)                 // 6400
#define WSLOT (Mdim * WAVES_PER_M)         // 20096 part slots
#define TWO_PI_F 6.28318530717958647692f
#define INV_2PI_F 0.15915494309189535f
#define NLOG2E_F (-1.4426950408889634f)
#define LOG2_10TH (-3.3219280948873623f)   // log2(0.1)

typedef float v2 __attribute__((ext_vector_type(2)));

__device__ __forceinline__ v2 mk2(float a, float b) { v2 r; r.x = a; r.y = b; return r; }
__device__ __forceinline__ v2 sel2(bool cx, bool cy, v2 a, v2 b) {
    return mk2(cx ? a.x : b.x, cy ? a.y : b.y);
}
__device__ __forceinline__ v2 sin2(v2 a) {
    return mk2(__builtin_amdgcn_sinf(a.x), __builtin_amdgcn_sinf(a.y));
}
__device__ __forceinline__ v2 cos2(v2 a) {
    return mk2(__builtin_amdgcn_cosf(a.x), __builtin_amdgcn_cosf(a.y));
}
__device__ __forceinline__ v2 exp22(v2 a) {
    return mk2(__builtin_amdgcn_exp2f(a.x), __builtin_amdgcn_exp2f(a.y));
}

// Per-layer, m-uniform, omega-free parameters. 32 B -> 2x ds_read_b128.
// dm pre-folded with trans-argument scalings (saves 2 v2 muls/layer);
// inv_rho2 recomputed as inv_rm^2 (1 op) to keep the struct at 8 floats.
struct alignas(16) LayerP {
    float inv_a2;    // 1/a^2
    float inv_b2;    // 1/b^2
    float b2two;     // 2*b^2
    float rm;        // rho
    float inv_rm;    // 1/rho
    float rho2;      // rho^2
    float dm_i2p;    // dm / (2*pi)   (v_sin/v_cos take revolutions)
    float dm_nle;    // dm * -log2(e) (exp(-p) = exp2(-p*log2e))
};

// One layer of the Dunkin recursion on a packed eval pair.
// x = ra2*w and z = rb2*y identities eliminate the x/z select chains.
// Regime is monotone in c (ra2>0 <=> c<a_layer), so waves are frequently
// regime-UNIFORM per side: branch on __all() (wave-uniform scalar branch)
// and skip the unused transcendental pair (sin+cos or exp).
template <bool RENORM>
__device__ __forceinline__ void layer_step(const LayerP& L,
                                           v2 wvno2, v2 wvno4, v2 tneg, v2 om2, v2 invom2,
                                           v2& e0, v2& e1, v2& e2, v2& e3, v2& e4)
{
    const v2 ra2 = wvno2 - om2 * L.inv_a2;   // sign = regime
    const v2 rb2 = wvno2 - om2 * L.inv_b2;

    // rsq replaces sqrt+rcp.
    const v2 inv_ra = mk2(__builtin_amdgcn_rsqf(fabsf(ra2.x)),
                          __builtin_amdgcn_rsqf(fabsf(ra2.y)));
    const v2 inv_rb = mk2(__builtin_amdgcn_rsqf(fabsf(rb2.x)),
                          __builtin_amdgcn_rsqf(fabsf(rb2.y)));
    const v2 ra = mk2(fabsf(ra2.x), fabsf(ra2.y)) * inv_ra;
    const v2 rb = mk2(fabsf(rb2.x), fabsf(rb2.y)) * inv_rb;
    const v2 gammk = L.b2two * invom2;
    const v2 gam   = gammk * wvno2;

    const bool lt_ax = ra2.x < 0.0f, lt_ay = ra2.y < 0.0f;
    const bool lt_bx = rb2.x < 0.0f, lt_by = rb2.y < 0.0f;
    const v2 one = mk2(1.0f, 1.0f);

    // ---- p-side (a regime) ----
    v2 cosp, w, a0p;
    if (__all(!lt_ax && !lt_ay)) {
        // uniformly evanescent: no sin/cos
        const v2 pe    = ra * L.dm_nle;
        const v2 e_p   = exp22(pe);
        const v2 fac_p = e_p * e_p;              // exp(-2p)
        cosp = 0.5f * fac_p + 0.5f;
        w    = (-0.5f * fac_p + 0.5f) * inv_ra;
        a0p  = e_p;
    } else if (__all(lt_ax && lt_ay)) {
        // uniformly propagating: no exp
        const v2 ppr = ra * L.dm_i2p;
        cosp = cos2(ppr);
        w    = sin2(ppr) * inv_ra;
        a0p  = one;
    } else {
        const v2 ppr   = ra * L.dm_i2p;
        const v2 pe    = ra * L.dm_nle;
        const v2 sp    = sin2(ppr);
        const v2 cp    = cos2(ppr);
        const v2 e_p   = exp22(pe);
        const v2 fac_p = e_p * e_p;
        cosp = sel2(lt_ax, lt_ay, cp, 0.5f * fac_p + 0.5f);
        w    = sel2(lt_ax, lt_ay, sp, -0.5f * fac_p + 0.5f) * inv_ra;
        a0p  = sel2(lt_ax, lt_ay, one, e_p);
    }

    // ---- q-side (b regime) ----
    v2 cosq, y, a0q;
    if (__all(!lt_bx && !lt_by)) {
        const v2 qe    = rb * L.dm_nle;
        const v2 e_q   = exp22(qe);
        const v2 fac_q = e_q * e_q;
        cosq = 0.5f * fac_q + 0.5f;
        y    = (-0.5f * fac_q + 0.5f) * inv_rb;
        a0q  = e_q;
    } else if (__all(lt_bx && lt_by)) {
        const v2 qqr = rb * L.dm_i2p;
        cosq = cos2(qqr);
        y    = sin2(qqr) * inv_rb;
        a0q  = one;
    } else {
        const v2 qqr   = rb * L.dm_i2p;
        const v2 qe    = rb * L.dm_nle;
        const v2 sq    = sin2(qqr);
        const v2 cq    = cos2(qqr);
        const v2 e_q   = exp22(qe);
        const v2 fac_q = e_q * e_q;
        cosq = sel2(lt_bx, lt_by, cq, 0.5f * fac_q + 0.5f);
        y    = sel2(lt_bx, lt_by, sq, -0.5f * fac_q + 0.5f) * inv_rb;
        a0q  = sel2(lt_bx, lt_by, one, e_q);
    }

    const v2 a0 = a0p * a0q;

    const v2 cpcq = cosp * cosq;
    const v2 cpy  = cosp * y;
    const v2 cqw  = cosq * w;
    const v2 wy   = w * y;
    const v2 cpz  = rb2 * cpy;
    const v2 cqx  = ra2 * cqw;
    const v2 wz   = rb2 * wy;
    const v2 xy   = ra2 * wy;
    const v2 xz   = ra2 * wz;

    // ---- _dnka (c20/c21/c23/c24 folded into et2 = tneg*e2) ----
    const v2 gamm1 = gam - 1.0f;
    const v2 twgm1 = gam + gamm1;
    const v2 gmgmk = gam * gammk;
    const v2 gmgm1 = gam * gamm1;
    const v2 gm1sq = gamm1 * gamm1;
    const v2 a0pq  = a0 - cpcq;
    const float irho2 = L.inv_rm * L.inv_rm;

    const v2 c00 = cpcq - 2.0f * gmgm1 * a0pq - gmgmk * xz - wvno2 * gm1sq * wy;
    const v2 c01 = (wvno2 * cpy - cqx) * L.inv_rm;
    const v2 c02 = -(twgm1 * a0pq + gammk * xz + wvno2 * gamm1 * wy) * L.inv_rm;
    const v2 c03 = (cpz - wvno2 * cqw) * L.inv_rm;
    const v2 c04 = -(2.0f * wvno2 * a0pq + xz + wvno4 * wy) * irho2;
    const v2 c10 = (gmgmk * cpz - gm1sq * cqw) * L.rm;
    const v2 c11 = cpcq;
    const v2 c12 = gammk * cpz - gamm1 * cqw;
    const v2 c13 = -wz;
    const v2 c30 = (gm1sq * cpy - gmgmk * cqx) * L.rm;
    const v2 c31 = -xy;
    const v2 c32 = gamm1 * cpy - gammk * cqx;
    const v2 c40 = -(2.0f * gmgmk * gm1sq * a0pq + gmgmk * gmgmk * xz
                     + gm1sq * gm1sq * wy) * L.rho2;
    const v2 c42 = -(gammk * gamm1 * twgm1 * a0pq + gam * gammk * gammk * xz
                     + gamm1 * gm1sq * wy) * L.rm;
    const v2 c22 = a0 + 2.0f * (cpcq - c00);

    const v2 et2 = tneg * e2;   // folds the tneg-scaled row-2 coefficients

    // ---- ee = e . ca ----
    const v2 ee0 = e0 * c00 + e1 * c10 + et2 * c42 + e3 * c30 + e4 * c40;
    const v2 ee1 = e0 * c01 + e1 * c11 + et2 * c32 + e3 * c31 + e4 * c30;
    const v2 ee2 = e0 * c02 + e1 * c12 + e2  * c22 + e3 * c32 + e4 * c42;
    const v2 ee3 = e0 * c03 + e1 * c13 + et2 * c12 + e3 * c11 + e4 * c10;
    const v2 ee4 = e0 * c04 + e1 * c03 + et2 * c02 + e3 * c01 + e4 * c00;

    if constexpr (RENORM) {
        float t1x = fmaxf(fmaxf(fabsf(ee0.x), fabsf(ee1.x)), fabsf(ee2.x));
        t1x = fmaxf(t1x, fmaxf(fabsf(ee3.x), fabsf(ee4.x)));
        float t1y = fmaxf(fmaxf(fabsf(ee0.y), fabsf(ee1.y)), fabsf(ee2.y));
        t1y = fmaxf(t1y, fmaxf(fabsf(ee3.y), fabsf(ee4.y)));
        t1x = fmaxf(t1x, 1e-30f);
        t1y = fmaxf(t1y, 1e-30f);
        const v2 inv = mk2(__builtin_amdgcn_rcpf(t1x), __builtin_amdgcn_rcpf(t1y));
        e0 = ee0 * inv;
        e1 = ee1 * inv;
        e2 = ee2 * inv;
        e3 = ee3 * inv;
        e4 = ee4 * inv;
    } else {
        e0 = ee0; e1 = ee1; e2 = ee2; e3 = ee3; e4 = ee4;
    }
}

// Packed Dunkin-recursion determinant: TWO independent evals per lane.
__device__ __forceinline__ v2 dltar4_pk(v2 wvno2, v2 om2, v2 invom2,
                                        const LayerP* __restrict__ slay)
{
    const v2 wvno4 = wvno2 * wvno2;
    const v2 tneg  = -2.0f * wvno2;

    // ---- halfspace init ----
    const LayerP H = slay[Ldim - 1];
    const v2 ra2h = wvno2 - om2 * H.inv_a2;
    const v2 rb2h = wvno2 - om2 * H.inv_b2;
    const v2 ra_h = mk2(__builtin_amdgcn_sqrtf(fabsf(ra2h.x)),
                        __builtin_amdgcn_sqrtf(fabsf(ra2h.y)));
    const v2 rb_h = mk2(__builtin_amdgcn_sqrtf(fabsf(rb2h.x)),
                        __builtin_amdgcn_sqrtf(fabsf(rb2h.y)));
    const v2 gammk_h = H.b2two * invom2;
    const v2 gam_h   = gammk_h * wvno2;
    const v2 gamm1_h = gam_h - 1.0f;
    const v2 rarb_h  = ra_h * rb_h;
    v2 e0 = H.rho2 * (gamm1_h * gamm1_h - gam_h * gammk_h * rarb_h);
    v2 e1 = -H.rm * ra_h;
    v2 e2 = H.rm * (gamm1_h - gammk_h * rarb_h);
    v2 e3 = H.rm * rb_h;
    v2 e4 = wvno2 - rarb_h;

    // l = 30 (even -> renorm), then 15 pairs (29,28) .. (1,0).
    layer_step<true>(slay[Ldim - 2], wvno2, wvno4, tneg, om2, invom2,
                     e0, e1, e2, e3, e4);
    for (int l = Ldim - 3; l >= 1; l -= 2) {
        layer_step<false>(slay[l],     wvno2, wvno4, tneg, om2, invom2,
                          e0, e1, e2, e3, e4);
        layer_step<true> (slay[l - 1], wvno2, wvno4, tneg, om2, invom2,
                          e0, e1, e2, e3, e4);
    }
    return e0;
}

// Main kernel: TWO evals per lane. Block = 4 waves, all same m.
// Wave wv covers flat evals [S, S+128). Per-wave segment max/min go to
// DEDICATED slots (pAmx/pAmn for the wave's first p, pBmx/pBmn for the
// crossed-into p) -- plain stores, no init kernel, no atomics. Sentinel
// +/-FLT_MAX are the neutral elements for partially-covering waves.
__global__ __launch_bounds__(256, 5)
void disp_kernel(const float* __restrict__ vlist, const float* __restrict__ tlist,
                 const float* __restrict__ dth,  const float* __restrict__ bvel,
                 const float* __restrict__ Clist,
                 float* __restrict__ pAmx, float* __restrict__ pAmn,
                 float* __restrict__ pBmx, float* __restrict__ pBmn,
                 float* __restrict__ e00f)
{
    __shared__ LayerP slay[Ldim];

    const int bid = blockIdx.x;
    const int m   = bid / BLOCKS_PER_M;
    const int wb  = bid - m * BLOCKS_PER_M;
    const int tid  = threadIdx.x;
    const int wid  = tid >> 6;
    const int lane = tid & 63;
    const int wv   = wb * 4 + wid;            // wave index within m

    if (tid < Ldim) {
        const float bb = bvel[m * Ldim + tid];
        const float b2 = bb * bb;
        const float b3 = b2 * bb;
        const float b4 = b2 * b2;
        const float aa = 0.9409f + 2.0947f * bb - 0.8206f * b2
                         + 0.2683f * b3 - 0.0251f * b4;
        const float a2 = aa * aa;
        const float a3 = a2 * aa;
        const float a4 = a2 * a2;
        const float a5 = a4 * aa;
        const float rr = 1.6612f * aa - 0.4721f * a2 + 0.0671f * a3
                         - 0.0043f * a4 + 0.000106f * a5;
        const float dmv = dth[m * Ldim + tid];
        LayerP Lp;
        Lp.inv_a2 = 1.0f / (aa * aa);
        Lp.inv_b2 = 1.0f / (bb * bb);
        Lp.b2two  = 2.0f * bb * bb;
        Lp.rm     = rr;
        Lp.inv_rm = 1.0f / rr;
        Lp.rho2   = rr * rr;
        Lp.dm_i2p = dmv * INV_2PI_F;
        Lp.dm_nle = dmv * NLOG2E_F;
        slay[tid] = Lp;
    }
    __syncthreads();

    if (wv >= WAVES_PER_M) return;            // idle waves (after barrier)

    // Decode (p, c) for both evals of this lane.
    const int S  = wv * EVALS_PER_WAVE;
    const int p0 = S / EVALS_PER_P;           // magic-mul const divide
    const int c0 = S - p0 * EVALS_PER_P;

    int cx = c0 + lane;
    const bool crx = cx >= EVALS_PER_P;
    const int px = p0 + (crx ? 1 : 0);
    cx = crx ? cx - EVALS_PER_P : cx;
    const bool validx = px < Pdim;

    int cy = c0 + 64 + lane;
    const bool cry = cy >= EVALS_PER_P;
    const int py = p0 + (cry ? 1 : 0);
    cy = cry ? cy - EVALS_PER_P : cy;
    const bool validy = py < Pdim;

    const int mpx = m * Pdim + (validx ? px : 0);
    const int mpy = m * Pdim + (validy ? py : 0);
    const float omx = fmaxf(TWO_PI_F / tlist[mpx], 1.0e-4f);
    const float omy = fmaxf(TWO_PI_F / tlist[mpy], 1.0e-4f);
    const bool isCx = cx < NCdim;
    const bool isCy = cy < NCdim;
    const float denx = isCx ? Clist[cx] : vlist[mpx];
    const float deny = isCy ? Clist[cy] : vlist[mpy];
    const float wvx = omx * __builtin_amdgcn_rcpf(denx);
    const float wvy = omy * __builtin_amdgcn_rcpf(deny);

    const v2 om2    = mk2(omx * omx, omy * omy);
    const v2 invom2 = mk2(__builtin_amdgcn_rcpf(om2.x), __builtin_amdgcn_rcpf(om2.y));
    const v2 wvno2  = mk2(wvx * wvx, wvy * wvy);

    const v2 det = dltar4_pk(wvno2, om2, invom2, slay);

    // e00 stores (exactly one lane/eval per (m,p) has c == NCdim).
    if (validx && !isCx) e00f[m * Pdim + px] = det.x;
    if (validy && !isCy) e00f[m * Pdim + py] = det.y;

    // Segmented reduction over the wave's <=2 p-segments (pA/pB wave-uniform).
    const int pA = p0;
    const int pB = p0 + ((c0 + EVALS_PER_WAVE - 1) >= EVALS_PER_P ? 1 : 0);
    const int slot = m * WAVES_PER_M + wv;

    {
        const bool inAx = validx && isCx && (px == pA);
        const bool inAy = validy && isCy && (py == pA);
        float mxA = fmaxf(inAx ? det.x : -FLT_MAX, inAy ? det.y : -FLT_MAX);
        float mnA = fminf(inAx ? det.x :  FLT_MAX, inAy ? det.y :  FLT_MAX);
        for (int off = 32; off >= 1; off >>= 1) {
            mxA = fmaxf(mxA, __shfl_xor(mxA, off));
            mnA = fminf(mnA, __shfl_xor(mnA, off));
        }
        if (lane == 0) {
            pAmx[slot] = mxA;
            pAmn[slot] = mnA;
        }
    }
    if (pB != pA) {                           // wave-uniform branch
        const bool inBx = validx && isCx && (px == pB);
        const bool inBy = validy && isCy && (py == pB);
        float mxB = fmaxf(inBx ? det.x : -FLT_MAX, inBy ? det.y : -FLT_MAX);
        float mnB = fminf(inBx ? det.x :  FLT_MAX, inBy ? det.y :  FLT_MAX);
        for (int off = 32; off >= 1; off >>= 1) {
            mxB = fmaxf(mxB, __shfl_xor(mxB, off));
            mnB = fminf(mnB, __shfl_xor(mnB, off));
        }
        if (lane == 0 && pB < Pdim) {
            pBmx[slot] = mxB;
            pBmn[slot] = mnB;
        }
    }
}

// Epilogue: one wave per m. Reconstructs per-p max/min from the <=5 covering
// wave slots, sums the 100 per-p terms + damping, writes out[m].
__global__ __launch_bounds__(64)
void epilogue_kernel(const float* __restrict__ pAmx, const float* __restrict__ pAmn,
                     const float* __restrict__ pBmx, const float* __restrict__ pBmn,
                     const float* __restrict__ e00f, const float* __restrict__ bvel,
                     float* __restrict__ out)
{
    const int m    = blockIdx.x;
    const int lane = threadIdx.x;

    float acc = 0.0f;
    for (int p = lane; p < Pdim; p += 64) {
        const int w0 = (EVALS_PER_P * p) / EVALS_PER_WAVE;
        const int w1 = (EVALS_PER_P * p + NCdim - 1) / EVALS_PER_WAVE;
        float mx = -FLT_MAX, mn = FLT_MAX;
        for (int w = w0; w <= w1; ++w) {
            const int s = m * WAVES_PER_M + w;
            const int pAw = (w * EVALS_PER_WAVE) / EVALS_PER_P;
            const float vmx = (pAw == p) ? pAmx[s] : pBmx[s];
            const float vmn = (pAw == p) ? pAmn[s] : pBmn[s];
            mx = fmaxf(mx, vmx);
            mn = fminf(mn, vmn);
        }
        const float en = e00f[m * Pdim + p] / (mx - mn);
        acc += 1.0f - __builtin_amdgcn_exp2f(fabsf(en) * LOG2_10TH); // 1-0.1^|en|
    }

    // damping term
    float damp = 0.0f;
    if (lane < Ldim) {
        const float bb    = bvel[m * Ldim + lane];
        const float bprev = bvel[m * Ldim + ((lane == 0) ? 0 : lane - 1)];
        const float bnext = bvel[m * Ldim + ((lane == Ldim - 1) ? Ldim - 1 : lane + 1)];
        float tval;
        if (lane == 0)             tval = bb - bnext;
        else if (lane == Ldim - 1) tval = bb - bprev;
        else                       tval = 2.0f * bb - bprev - bnext;
        damp = fabsf(tval * (1.0f / (float)Ldim));
    }

    float tot = fmaf(acc, 1.0f / (float)Pdim, damp);
    for (int off = 32; off >= 1; off >>= 1)
        tot += __shfl_xor(tot, off);
    if (lane == 0) out[m] = tot;
}

extern "C" void kernel_launch(void* const* d_in, const int* in_sizes, int n_in,
                              void* d_out, int out_size, void* d_ws, size_t ws_size,
                              hipStream_t stream)
{
    const float* vlist = (const float*)d_in[0];
    const float* tlist = (const float*)d_in[1];
    const float* dth   = (const float*)d_in[2];
    const float* bvel  = (const float*)d_in[3];
    const float* Clist = (const float*)d_in[4];
    float* out = (float*)d_out;

    float* pAmx = (float*)d_ws;            // [WSLOT]
    float* pAmn = pAmx + WSLOT;
    float* pBmx = pAmn + WSLOT;
    float* pBmn = pBmx + WSLOT;
    float* e00f = pBmn + WSLOT;            // [NPTS]

    hipLaunchKernelGGL(disp_kernel, dim3(Mdim * BLOCKS_PER_M), dim3(256), 0, stream,
                       vlist, tlist, dth, bvel, Clist, pAmx, pAmn, pBmx, pBmn, e00f);
    hipLaunchKernelGGL(epilogue_kernel, dim3(Mdim), dim3(64), 0, stream,
                       pAmx, pAmn, pBmx, pBmn, e00f, bvel, out);
}